// Round 4
// baseline (519.878 us; speedup 1.0000x reference)
//
#include <hip/hip_runtime.h>
#include <hip/hip_bf16.h>

typedef __hip_bfloat16 bf16;

#define ROWS 204800
#define N_INV (1.0f / 204800.0f)

// --- static device scratch: no reliance on d_ws at all -----------------------
__device__ float g_stats[256];            // sum1[64] sumsq1[64] sum2[32] sumsq2[32] pad
__device__ float g_E1_1[1000 * 64];
__device__ float g_E1_2[100 * 64];
__device__ float g_E1_3[50 * 64];
__device__ float g_U[8 * 64];
__device__ float g_Vb[64];
__device__ bf16  g_h1p[ROWS * 64];        // 26.2 MB bf16 h1_pre staging

__device__ __forceinline__ int clampi(int v, int hi) {
    return v < 0 ? 0 : (v > hi ? hi : v);
}

// ---------------------------------------------------------------------------
// Kernel A: E1_t = emb_t @ W1_t^T (t=1..3), U = cont_w @ W1_cont^T,
// Vb = b1 + sum_j cont_b[j] @ W1_cont_j^T. Block 1150 zeroes the stat block.
// ---------------------------------------------------------------------------
__global__ __launch_bounds__(64) void precompute_kernel(
    const float* __restrict__ emb1, const float* __restrict__ emb2, const float* __restrict__ emb3,
    const float* __restrict__ cont_w, const float* __restrict__ cont_b,
    const float* __restrict__ w1, const float* __restrict__ b1)
{
    int b = blockIdx.x;
    int k = threadIdx.x;        // 0..63 output channel
    __shared__ float row[32];

    if (b < 1150) {
        const float* tab; float* out; int i, colOff;
        if (b < 1000)      { tab = emb1; out = g_E1_1; i = b;        colOff = 32; }
        else if (b < 1100) { tab = emb2; out = g_E1_2; i = b - 1000; colOff = 64; }
        else               { tab = emb3; out = g_E1_3; i = b - 1100; colOff = 96; }
        if (k < 32) row[k] = tab[i * 32 + k];
        __syncthreads();
        const float* wr = w1 + k * 384 + colOff;
        float acc = 0.f;
        #pragma unroll
        for (int d = 0; d < 32; ++d) acc = fmaf(row[d], wr[d], acc);
        out[i * 64 + k] = acc;
    } else {
        g_stats[k]       = 0.f;
        g_stats[k + 64]  = 0.f;
        g_stats[k + 128] = 0.f;
        g_stats[k + 192] = 0.f;

        float vb = b1[k];
        #pragma unroll
        for (int j = 0; j < 8; ++j) {
            const float* wr = w1 + k * 384 + (4 + j) * 32;
            float u = 0.f;
            #pragma unroll
            for (int d = 0; d < 32; ++d) {
                float w = wr[d];
                u  = fmaf(cont_w[j * 32 + d], w, u);
                vb = fmaf(cont_b[j * 32 + d], w, vb);
            }
            g_U[j * 64 + k] = u;
        }
        g_Vb[k] = vb;
    }
}

// ---------------------------------------------------------------------------
// Kernel B (phase 1): FM partial (linear+interaction) -> fp32 into d_out;
// h1_pre = h @ w1^T + b1 (factorized) -> bf16 into g_h1p; layer-1 stats.
// One wave per 25 rows, 4 waves/block.
// ---------------------------------------------------------------------------
__global__ __launch_bounds__(256) void phase1_kernel(
    const float* __restrict__ x,
    const float* __restrict__ emb0, const float* __restrict__ lin0,
    const float* __restrict__ emb1, const float* __restrict__ lin1,
    const float* __restrict__ emb2, const float* __restrict__ lin2,
    const float* __restrict__ emb3, const float* __restrict__ lin3,
    const float* __restrict__ cont_w, const float* __restrict__ cont_b,
    const float* __restrict__ clin_w, const float* __restrict__ clin_b,
    const float* __restrict__ fin_bias, const float* __restrict__ w1,
    float* __restrict__ fm_out)
{
    __shared__ float w10[32 * 64];     // W1 feature-0 slice, [d][k]
    __shared__ float e0buf[4][32];
    __shared__ float lsum[64], lsq[64];

    int tid  = threadIdx.x;
    int lane = tid & 63;
    int wv   = tid >> 6;

    for (int idx = tid; idx < 2048; idx += 256) {
        int d = idx >> 6, k = idx & 63;
        w10[idx] = w1[k * 384 + d];
    }
    if (tid < 64) { lsum[tid] = 0.f; lsq[tid] = 0.f; }

    int d = lane & 31;
    float cw[8], cb[8], lw[8], lb[8], fb = 0.f;
    if (lane < 32) {
        #pragma unroll
        for (int j = 0; j < 8; ++j) { cw[j] = cont_w[j * 32 + d]; cb[j] = cont_b[j * 32 + d]; }
        #pragma unroll
        for (int j = 0; j < 8; ++j) { lw[j] = 0.f; lb[j] = 0.f; }
    } else {
        #pragma unroll
        for (int j = 0; j < 8; ++j) { lw[j] = clin_w[j * 32 + d]; lb[j] = clin_b[j * 32 + d]; }
        #pragma unroll
        for (int j = 0; j < 8; ++j) { cw[j] = 0.f; cb[j] = 0.f; }
        fb = fin_bias[d];
    }
    float uk_v[8];
    #pragma unroll
    for (int j = 0; j < 8; ++j) uk_v[j] = g_U[j * 64 + lane];
    float vbk = g_Vb[lane];
    __syncthreads();

    int gw   = blockIdx.x * 4 + wv;    // 0..8191
    int base = gw * 25;
    float ss = 0.f, qq = 0.f;

    for (int it = 0; it < 25; ++it) {
        int r = base + it;

        float xv = (lane < 12) ? x[r * 12 + lane] : 0.f;
        int i0 = clampi((int)__shfl(xv, 0), 99999);
        int i1 = clampi((int)__shfl(xv, 1), 999);
        int i2 = clampi((int)__shfl(xv, 2), 99);
        int i3 = clampi((int)__shfl(xv, 3), 49);
        float xc[8];
        #pragma unroll
        for (int j = 0; j < 8; ++j) xc[j] = __shfl(xv, 4 + j);

        float inter = 0.f, lin = 0.f;
        if (lane < 32) {
            float e0 = emb0[i0 * 32 + d];
            float e1 = emb1[i1 * 32 + d];
            float e2 = emb2[i2 * 32 + d];
            float e3 = emb3[i3 * 32 + d];
            float s = e0 + e1 + e2 + e3;
            float q = e0 * e0 + e1 * e1 + e2 * e2 + e3 * e3;
            #pragma unroll
            for (int j = 0; j < 8; ++j) {
                float ce = fmaf(xc[j], cw[j], cb[j]);
                s += ce;
                q = fmaf(ce, ce, q);
            }
            inter = 0.5f * (s * s - q);
            e0buf[wv][d] = e0;
        } else {
            float l0 = lin0[i0 * 32 + d];
            float l1 = lin1[i1 * 32 + d];
            float l2 = lin2[i2 * 32 + d];
            float l3 = lin3[i3 * 32 + d];
            lin = l0 + l1 + l2 + l3 + fb;
            #pragma unroll
            for (int j = 0; j < 8; ++j) lin += fmaf(xc[j], lw[j], lb[j]);
        }
        __syncthreads();

        float lin_o = __shfl(lin, lane | 32);
        if (lane < 32) fm_out[r * 32 + d] = inter + lin_o;

        int k = lane;
        float h1 = vbk + g_E1_1[i1 * 64 + k] + g_E1_2[i2 * 64 + k] + g_E1_3[i3 * 64 + k];
        #pragma unroll
        for (int j = 0; j < 8; ++j) h1 = fmaf(xc[j], uk_v[j], h1);
        #pragma unroll
        for (int dd = 0; dd < 32; ++dd) h1 = fmaf(e0buf[wv][dd], w10[dd * 64 + k], h1);

        g_h1p[r * 64 + k] = __float2bfloat16(h1);
        ss += h1;
        qq = fmaf(h1, h1, qq);
        __syncthreads();
    }

    atomicAdd(&lsum[lane], ss);
    atomicAdd(&lsq[lane], qq);
    __syncthreads();
    if (tid < 64) {
        atomicAdd(&g_stats[tid], lsum[tid]);        // sum1
        atomicAdd(&g_stats[64 + tid], lsq[tid]);    // sumsq1
    }
}

// ---------------------------------------------------------------------------
// Kernel C (phase 2): y1 = relu(a1*h1_pre + c1); h2 = y1 @ w2^T + b2.
// Layer-2 stats only (h2 recomputed bitwise-identically in phase 3).
// ---------------------------------------------------------------------------
__global__ __launch_bounds__(256) void phase2_kernel(
    const float* __restrict__ w2, const float* __restrict__ b2,
    const float* __restrict__ g1, const float* __restrict__ beta1)
{
    __shared__ float w2s[64 * 32];     // [k][m]
    __shared__ float y1buf[4][64];
    __shared__ float lsum[32], lsq[32];

    int tid  = threadIdx.x;
    int lane = tid & 63;
    int wv   = tid >> 6;

    for (int idx = tid; idx < 2048; idx += 256) {
        int k = idx >> 5, m = idx & 31;
        w2s[idx] = w2[m * 64 + k];
    }
    if (tid < 32) { lsum[tid] = 0.f; lsq[tid] = 0.f; }

    float S  = g_stats[lane], Q = g_stats[64 + lane];
    float mu = S * N_INV;
    float var = Q * N_INV - mu * mu;
    float a1 = g1[lane] * rsqrtf(var + 1e-5f);
    float c1 = beta1[lane] - a1 * mu;
    float b2m = (lane < 32) ? b2[lane] : 0.f;
    __syncthreads();

    int gw   = blockIdx.x * 4 + wv;
    int base = gw * 25;
    float ss = 0.f, qq = 0.f;

    for (int it = 0; it < 25; ++it) {
        int r = base + it;
        float h1v = __bfloat162float(g_h1p[r * 64 + lane]);
        y1buf[wv][lane] = fmaxf(0.f, fmaf(a1, h1v, c1));
        __syncthreads();
        if (lane < 32) {
            int m = lane;
            float h2 = b2m;
            #pragma unroll
            for (int k = 0; k < 64; ++k) h2 = fmaf(y1buf[wv][k], w2s[k * 32 + m], h2);
            ss += h2;
            qq = fmaf(h2, h2, qq);
        }
        __syncthreads();
    }

    if (lane < 32) {
        atomicAdd(&lsum[lane], ss);
        atomicAdd(&lsq[lane], qq);
    }
    __syncthreads();
    if (tid < 32) {
        atomicAdd(&g_stats[128 + tid], lsum[tid]);  // sum2
        atomicAdd(&g_stats[160 + tid], lsq[tid]);   // sumsq2
    }
}

// ---------------------------------------------------------------------------
// Kernel D (phase 3): recompute h2 from h1_pre, BN2+relu, output head,
// add the FM partial staged in d_out. Wave per row.
// ---------------------------------------------------------------------------
__global__ __launch_bounds__(256) void phase3_kernel(
    const float* __restrict__ w2, const float* __restrict__ b2,
    const float* __restrict__ g1, const float* __restrict__ beta1,
    const float* __restrict__ w_out, const float* __restrict__ b_out,
    const float* __restrict__ g2, const float* __restrict__ beta2,
    float* __restrict__ out)   // holds FM partial on entry
{
    __shared__ float w2s[64 * 32];     // [k][m]
    __shared__ float wos[32 * 32];     // [k][d]
    __shared__ float y1buf[4][64];
    __shared__ float y2buf[4][32];

    int tid  = threadIdx.x;
    int lane = tid & 63;
    int wv   = tid >> 6;
    int m    = lane & 31;

    for (int idx = tid; idx < 2048; idx += 256) {
        int k = idx >> 5, mm = idx & 31;
        w2s[idx] = w2[mm * 64 + k];
    }
    for (int idx = tid; idx < 1024; idx += 256) {
        int k = idx >> 5, dd = idx & 31;
        wos[idx] = w_out[dd * 32 + k];
    }

    float S1 = g_stats[lane], Q1 = g_stats[64 + lane];
    float mu1 = S1 * N_INV;
    float v1  = Q1 * N_INV - mu1 * mu1;
    float a1  = g1[lane] * rsqrtf(v1 + 1e-5f);
    float c1  = beta1[lane] - a1 * mu1;

    float S2 = g_stats[128 + m], Q2 = g_stats[160 + m];
    float mu2 = S2 * N_INV;
    float v2  = Q2 * N_INV - mu2 * mu2;
    float a2  = g2[m] * rsqrtf(v2 + 1e-5f);
    float c2  = beta2[m] - a2 * mu2;
    float b2m = b2[m];
    float bo  = b_out[m];
    __syncthreads();

    int gw   = blockIdx.x * 4 + wv;
    int base = gw * 25;

    for (int it = 0; it < 25; ++it) {
        int r = base + it;
        float h1v = __bfloat162float(g_h1p[r * 64 + lane]);
        y1buf[wv][lane] = fmaxf(0.f, fmaf(a1, h1v, c1));
        __syncthreads();
        if (lane < 32) {
            float h2 = b2m;
            #pragma unroll
            for (int k = 0; k < 64; ++k) h2 = fmaf(y1buf[wv][k], w2s[k * 32 + m], h2);
            y2buf[wv][m] = fmaxf(0.f, fmaf(a2, h2, c2));
        }
        __syncthreads();
        if (lane < 32) {
            int dd = m;
            float o = out[r * 32 + dd] + bo;
            #pragma unroll
            for (int k = 0; k < 32; ++k) o = fmaf(y2buf[wv][k], wos[k * 32 + dd], o);
            out[r * 32 + dd] = o;
        }
        __syncthreads();
    }
}

// ---------------------------------------------------------------------------
extern "C" void kernel_launch(void* const* d_in, const int* in_sizes, int n_in,
                              void* d_out, int out_size, void* d_ws, size_t ws_size,
                              hipStream_t stream) {
    (void)in_sizes; (void)n_in; (void)out_size; (void)d_ws; (void)ws_size;

    // setup_inputs() dict order (emb/lin interleaved!) — all float32
    const float* x       = (const float*)d_in[0];
    const float* emb0    = (const float*)d_in[1];
    const float* lin0    = (const float*)d_in[2];
    const float* emb1    = (const float*)d_in[3];
    const float* lin1    = (const float*)d_in[4];
    const float* emb2    = (const float*)d_in[5];
    const float* lin2    = (const float*)d_in[6];
    const float* emb3    = (const float*)d_in[7];
    const float* lin3    = (const float*)d_in[8];
    const float* cont_w  = (const float*)d_in[9];
    const float* cont_b  = (const float*)d_in[10];
    const float* clin_w  = (const float*)d_in[11];
    const float* clin_b  = (const float*)d_in[12];
    const float* fin_bias= (const float*)d_in[13];
    const float* w1      = (const float*)d_in[14];
    const float* b1      = (const float*)d_in[15];
    const float* g1      = (const float*)d_in[16];
    const float* beta1   = (const float*)d_in[17];
    const float* w2      = (const float*)d_in[18];
    const float* b2      = (const float*)d_in[19];
    const float* g2      = (const float*)d_in[20];
    const float* beta2   = (const float*)d_in[21];
    const float* w_out   = (const float*)d_in[22];
    const float* b_out   = (const float*)d_in[23];

    float* outp = (float*)d_out;               // also stages the FM partial

    hipLaunchKernelGGL(precompute_kernel, dim3(1151), dim3(64), 0, stream,
                       emb1, emb2, emb3, cont_w, cont_b, w1, b1);

    hipLaunchKernelGGL(phase1_kernel, dim3(2048), dim3(256), 0, stream,
                       x, emb0, lin0, emb1, lin1, emb2, lin2, emb3, lin3,
                       cont_w, cont_b, clin_w, clin_b, fin_bias, w1,
                       outp);

    hipLaunchKernelGGL(phase2_kernel, dim3(2048), dim3(256), 0, stream,
                       w2, b2, g1, beta1);

    hipLaunchKernelGGL(phase3_kernel, dim3(2048), dim3(256), 0, stream,
                       w2, b2, g1, beta1, w_out, b_out, g2, beta2,
                       outp);
}

// Round 5
// 394.809 us; speedup vs baseline: 1.3168x; 1.3168x over previous
//
#include <hip/hip_runtime.h>
#include <hip/hip_bf16.h>

typedef __hip_bfloat16 bf16;

#define ROWS 204800
#define N_INV (1.0f / 204800.0f)

// --- static device scratch (d_ws is NOT used; ws_size proved too small) ------
__device__ float g_stats[256];            // sum1[64] sumsq1[64] sum2[32] sumsq2[32]
__device__ float g_E1_1[1000 * 64];
__device__ float g_E1_2[100 * 64];
__device__ float g_E1_3[50 * 64];
__device__ float g_U[8 * 64];
__device__ float g_Vb[64];
__device__ bf16  g_h1p[ROWS * 64];        // 26.2 MB bf16 h1_pre staging
__device__ bf16  g_h2p[ROWS * 32];        // 13.1 MB bf16 h2_pre staging

__device__ __forceinline__ int clampi(int v, int hi) {
    return v < 0 ? 0 : (v > hi ? hi : v);
}

// ---------------------------------------------------------------------------
// Kernel A: E1_t = emb_t @ W1_t^T (t=1..3), U = cont_w @ W1_cont^T,
// Vb = b1 + sum_j cont_b[j] @ W1_cont_j^T. Block 1150 zeroes the stat block.
// ---------------------------------------------------------------------------
__global__ __launch_bounds__(64) void precompute_kernel(
    const float* __restrict__ emb1, const float* __restrict__ emb2, const float* __restrict__ emb3,
    const float* __restrict__ cont_w, const float* __restrict__ cont_b,
    const float* __restrict__ w1, const float* __restrict__ b1)
{
    int b = blockIdx.x;
    int k = threadIdx.x;        // 0..63 output channel
    __shared__ float row[32];

    if (b < 1150) {
        const float* tab; float* out; int i, colOff;
        if (b < 1000)      { tab = emb1; out = g_E1_1; i = b;        colOff = 32; }
        else if (b < 1100) { tab = emb2; out = g_E1_2; i = b - 1000; colOff = 64; }
        else               { tab = emb3; out = g_E1_3; i = b - 1100; colOff = 96; }
        if (k < 32) row[k] = tab[i * 32 + k];
        __syncthreads();
        const float* wr = w1 + k * 384 + colOff;
        float acc = 0.f;
        #pragma unroll
        for (int d = 0; d < 32; ++d) acc = fmaf(row[d], wr[d], acc);
        out[i * 64 + k] = acc;
    } else {
        g_stats[k]       = 0.f;
        g_stats[k + 64]  = 0.f;
        g_stats[k + 128] = 0.f;
        g_stats[k + 192] = 0.f;

        float vb = b1[k];
        #pragma unroll
        for (int j = 0; j < 8; ++j) {
            const float* wr = w1 + k * 384 + (4 + j) * 32;
            float u = 0.f;
            #pragma unroll
            for (int d = 0; d < 32; ++d) {
                float w = wr[d];
                u  = fmaf(cont_w[j * 32 + d], w, u);
                vb = fmaf(cont_b[j * 32 + d], w, vb);
            }
            g_U[j * 64 + k] = u;
        }
        g_Vb[k] = vb;
    }
}

// ---------------------------------------------------------------------------
// Phase 1 (barrier-free waves): FM partial -> fp32 d_out; h1_pre -> bf16 g_h1p;
// layer-1 stats via per-lane registers + one end-of-block LDS reduction.
// Lanes 0-31: interaction path (d=lane). Lanes 32-63: linear path (d=lane-32).
// e0 crosses lanes via __shfl — no LDS, no loop barriers.
// ---------------------------------------------------------------------------
__global__ __launch_bounds__(256) void phase1_kernel(
    const float* __restrict__ x,
    const float* __restrict__ emb0, const float* __restrict__ lin0,
    const float* __restrict__ emb1, const float* __restrict__ lin1,
    const float* __restrict__ emb2, const float* __restrict__ lin2,
    const float* __restrict__ emb3, const float* __restrict__ lin3,
    const float* __restrict__ cont_w, const float* __restrict__ cont_b,
    const float* __restrict__ clin_w, const float* __restrict__ clin_b,
    const float* __restrict__ fin_bias, const float* __restrict__ w1,
    float* __restrict__ fm_out)
{
    __shared__ float lsum[64], lsq[64];

    int tid  = threadIdx.x;
    int lane = tid & 63;
    int wv   = tid >> 6;
    int d    = lane & 31;
    bool lo  = lane < 32;

    if (tid < 64) { lsum[tid] = 0.f; lsq[tid] = 0.f; }
    __syncthreads();

    // per-lane W1 column for h1 channel k=lane (feature-0 slice, 32 floats)
    float w1col[32];
    {
        const float4* wr = (const float4*)(w1 + lane * 384);
        #pragma unroll
        for (int q = 0; q < 8; ++q) {
            float4 v = wr[q];
            w1col[4*q+0] = v.x; w1col[4*q+1] = v.y;
            w1col[4*q+2] = v.z; w1col[4*q+3] = v.w;
        }
    }
    float uk[8];
    #pragma unroll
    for (int j = 0; j < 8; ++j) uk[j] = g_U[j * 64 + lane];
    float vbk = g_Vb[lane];

    float p1[8], p2[8], fb = 0.f;
    if (lo) {
        #pragma unroll
        for (int j = 0; j < 8; ++j) { p1[j] = cont_w[j * 32 + d]; p2[j] = cont_b[j * 32 + d]; }
    } else {
        #pragma unroll
        for (int j = 0; j < 8; ++j) { p1[j] = clin_w[j * 32 + d]; p2[j] = clin_b[j * 32 + d]; }
        fb = fin_bias[d];
    }

    int gw   = blockIdx.x * 4 + wv;    // 0..8191
    int base = gw * 25;
    float ss = 0.f, qq = 0.f;

    float xv = (lane < 12) ? x[base * 12 + lane] : 0.f;

    for (int it = 0; it < 25; ++it) {
        int r = base + it;

        int i0 = clampi((int)__shfl(xv, 0), 99999);
        int i1 = clampi((int)__shfl(xv, 1), 999);
        int i2 = clampi((int)__shfl(xv, 2), 99);
        int i3 = clampi((int)__shfl(xv, 3), 49);
        float xc[8];
        #pragma unroll
        for (int j = 0; j < 8; ++j) xc[j] = __shfl(xv, 4 + j);

        // issue all independent loads up front
        float ga, gb, gc, gd;
        if (lo) {
            ga = emb0[i0 * 32 + d]; gb = emb1[i1 * 32 + d];
            gc = emb2[i2 * 32 + d]; gd = emb3[i3 * 32 + d];
        } else {
            ga = lin0[i0 * 32 + d]; gb = lin1[i1 * 32 + d];
            gc = lin2[i2 * 32 + d]; gd = lin3[i3 * 32 + d];
        }
        float t1 = g_E1_1[i1 * 64 + lane];
        float t2 = g_E1_2[i2 * 64 + lane];
        float t3 = g_E1_3[i3 * 64 + lane];
        float xvn = (it < 24 && lane < 12) ? x[(r + 1) * 12 + lane] : 0.f;

        // FM halves
        float half_val;
        if (lo) {
            float s = (ga + gb) + (gc + gd);
            float q = fmaf(ga, ga, gb * gb) + fmaf(gc, gc, gd * gd);
            #pragma unroll
            for (int j = 0; j < 8; ++j) {
                float ce = fmaf(xc[j], p1[j], p2[j]);
                s += ce;
                q = fmaf(ce, ce, q);
            }
            half_val = 0.5f * (s * s - q);                  // interaction
        } else {
            float l = (ga + gb) + (gc + gd) + fb;
            #pragma unroll
            for (int j = 0; j < 8; ++j) l = fmaf(xc[j], p1[j], l + p2[j]);
            half_val = l;                                   // linear
        }
        float other = __shfl(half_val, lane | 32);          // linear -> low lanes
        if (lo) fm_out[r * 32 + d] = half_val + other;

        // h1 channel k=lane
        float h1 = ((vbk + t1) + (t2 + t3));
        #pragma unroll
        for (int j = 0; j < 8; ++j) h1 = fmaf(xc[j], uk[j], h1);

        float a0 = 0.f, a1 = 0.f, a2 = 0.f, a3 = 0.f;
        #pragma unroll
        for (int dd = 0; dd < 32; dd += 4) {
            a0 = fmaf(__shfl(ga, dd + 0), w1col[dd + 0], a0);
            a1 = fmaf(__shfl(ga, dd + 1), w1col[dd + 1], a1);
            a2 = fmaf(__shfl(ga, dd + 2), w1col[dd + 2], a2);
            a3 = fmaf(__shfl(ga, dd + 3), w1col[dd + 3], a3);
        }
        h1 += (a0 + a1) + (a2 + a3);

        g_h1p[r * 64 + lane] = __float2bfloat16(h1);
        ss += h1;
        qq = fmaf(h1, h1, qq);
        xv = xvn;
    }

    atomicAdd(&lsum[lane], ss);
    atomicAdd(&lsq[lane], qq);
    __syncthreads();
    if (tid < 64) {
        atomicAdd(&g_stats[tid], lsum[tid]);        // sum1
        atomicAdd(&g_stats[64 + tid], lsq[tid]);    // sumsq1
    }
}

// ---------------------------------------------------------------------------
// Phase 2 (barrier-free waves): y1 = relu(a1*h1+c1); h2 = y1 @ w2^T + b2
// via split-K across half-waves (+shfl_xor combine); h2 -> bf16 g_h2p;
// layer-2 stats via registers + end-of-block LDS reduction.
// ---------------------------------------------------------------------------
__global__ __launch_bounds__(256) void phase2_kernel(
    const float* __restrict__ w2, const float* __restrict__ b2,
    const float* __restrict__ g1, const float* __restrict__ beta1)
{
    __shared__ float lsum[32], lsq[32];

    int tid  = threadIdx.x;
    int lane = tid & 63;
    int wv   = tid >> 6;
    int m    = lane & 31;
    int h    = lane >> 5;

    if (tid < 32) { lsum[tid] = 0.f; lsq[tid] = 0.f; }
    __syncthreads();

    // per-lane half-column of w2: w2[m][32h + kk], kk=0..31 (consecutive)
    float w2h[32];
    {
        const float4* wr = (const float4*)(w2 + m * 64 + 32 * h);
        #pragma unroll
        for (int q = 0; q < 8; ++q) {
            float4 v = wr[q];
            w2h[4*q+0] = v.x; w2h[4*q+1] = v.y;
            w2h[4*q+2] = v.z; w2h[4*q+3] = v.w;
        }
    }

    // BN1 affine for channel = lane
    float S  = g_stats[lane], Q = g_stats[64 + lane];
    float mu = S * N_INV;
    float var = Q * N_INV - mu * mu;
    float a1 = g1[lane] * rsqrtf(var + 1e-5f);
    float c1 = beta1[lane] - a1 * mu;
    float b2m = b2[m];

    int gw   = blockIdx.x * 4 + wv;
    int base = gw * 25;
    float ss = 0.f, qq = 0.f;

    bf16 hv = g_h1p[base * 64 + lane];

    for (int it = 0; it < 25; ++it) {
        int r = base + it;
        float y1 = fmaxf(0.f, fmaf(a1, __bfloat162float(hv), c1));
        if (it < 24) hv = g_h1p[(r + 1) * 64 + lane];

        float a0 = 0.f, aa1 = 0.f, a2 = 0.f, a3 = 0.f;
        #pragma unroll
        for (int kk = 0; kk < 32; kk += 4) {
            a0  = fmaf(__shfl(y1, 32 * h + kk + 0), w2h[kk + 0], a0);
            aa1 = fmaf(__shfl(y1, 32 * h + kk + 1), w2h[kk + 1], aa1);
            a2  = fmaf(__shfl(y1, 32 * h + kk + 2), w2h[kk + 2], a2);
            a3  = fmaf(__shfl(y1, 32 * h + kk + 3), w2h[kk + 3], a3);
        }
        float part = (a0 + aa1) + (a2 + a3);
        float h2 = part + __shfl_xor(part, 32) + b2m;   // full sum, lanes m and m+32

        if (h == 0) g_h2p[r * 32 + m] = __float2bfloat16(h2);
        ss += h2;                   // counted twice (both halves) — halved below
        qq = fmaf(h2, h2, qq);
    }

    atomicAdd(&lsum[m], ss);
    atomicAdd(&lsq[m], qq);
    __syncthreads();
    if (tid < 32) {
        atomicAdd(&g_stats[128 + tid], 0.5f * lsum[tid]);  // sum2
        atomicAdd(&g_stats[160 + tid], 0.5f * lsq[tid]);   // sumsq2
    }
}

// ---------------------------------------------------------------------------
// Phase 3 (barrier-free waves): y2 = relu(a2*h2+c2); out = fm + y2 @ w_out^T
// + b_out. Each half-wave owns one row stream (wave covers 50 rows).
// ---------------------------------------------------------------------------
__global__ __launch_bounds__(256) void phase3_kernel(
    const float* __restrict__ w_out, const float* __restrict__ b_out,
    const float* __restrict__ g2, const float* __restrict__ beta2,
    float* __restrict__ out)   // holds FM partial on entry
{
    int tid  = threadIdx.x;
    int lane = tid & 63;
    int wv   = tid >> 6;
    int m    = lane & 31;
    int h    = lane >> 5;

    // per-lane output row of w_out: w_out[m][k], k=0..31 (consecutive)
    float wo[32];
    {
        const float4* wr = (const float4*)(w_out + m * 32);
        #pragma unroll
        for (int q = 0; q < 8; ++q) {
            float4 v = wr[q];
            wo[4*q+0] = v.x; wo[4*q+1] = v.y;
            wo[4*q+2] = v.z; wo[4*q+3] = v.w;
        }
    }

    float S  = g_stats[128 + m], Q = g_stats[160 + m];
    float mu = S * N_INV;
    float var = Q * N_INV - mu * mu;
    float a2 = g2[m] * rsqrtf(var + 1e-5f);
    float c2 = beta2[m] - a2 * mu;
    float bo = b_out[m];

    int gw   = blockIdx.x * 4 + wv;        // 0..4095
    int base = gw * 50 + h * 25;           // each half-wave: 25 rows

    bf16  hv = g_h2p[base * 32 + m];
    float fv = out[base * 32 + m];

    for (int it = 0; it < 25; ++it) {
        int r = base + it;
        float y2 = fmaxf(0.f, fmaf(a2, __bfloat162float(hv), c2));
        float o  = fv + bo;
        if (it < 24) {
            hv = g_h2p[(r + 1) * 32 + m];
            fv = out[(r + 1) * 32 + m];
        }

        float a0 = 0.f, a1 = 0.f, aa2 = 0.f, a3 = 0.f;
        #pragma unroll
        for (int k = 0; k < 32; k += 4) {
            a0  = fmaf(__shfl(y2, 32 * h + k + 0), wo[k + 0], a0);
            a1  = fmaf(__shfl(y2, 32 * h + k + 1), wo[k + 1], a1);
            aa2 = fmaf(__shfl(y2, 32 * h + k + 2), wo[k + 2], aa2);
            a3  = fmaf(__shfl(y2, 32 * h + k + 3), wo[k + 3], a3);
        }
        out[r * 32 + m] = o + (a0 + a1) + (aa2 + a3);
    }
}

// ---------------------------------------------------------------------------
extern "C" void kernel_launch(void* const* d_in, const int* in_sizes, int n_in,
                              void* d_out, int out_size, void* d_ws, size_t ws_size,
                              hipStream_t stream) {
    (void)in_sizes; (void)n_in; (void)out_size; (void)d_ws; (void)ws_size;

    // setup_inputs() dict order (emb/lin interleaved!) — all float32
    const float* x       = (const float*)d_in[0];
    const float* emb0    = (const float*)d_in[1];
    const float* lin0    = (const float*)d_in[2];
    const float* emb1    = (const float*)d_in[3];
    const float* lin1    = (const float*)d_in[4];
    const float* emb2    = (const float*)d_in[5];
    const float* lin2    = (const float*)d_in[6];
    const float* emb3    = (const float*)d_in[7];
    const float* lin3    = (const float*)d_in[8];
    const float* cont_w  = (const float*)d_in[9];
    const float* cont_b  = (const float*)d_in[10];
    const float* clin_w  = (const float*)d_in[11];
    const float* clin_b  = (const float*)d_in[12];
    const float* fin_bias= (const float*)d_in[13];
    const float* w1      = (const float*)d_in[14];
    const float* b1      = (const float*)d_in[15];
    const float* g1      = (const float*)d_in[16];
    const float* beta1   = (const float*)d_in[17];
    const float* w2      = (const float*)d_in[18];
    const float* b2      = (const float*)d_in[19];
    const float* g2      = (const float*)d_in[20];
    const float* beta2   = (const float*)d_in[21];
    const float* w_out   = (const float*)d_in[22];
    const float* b_out   = (const float*)d_in[23];

    float* outp = (float*)d_out;               // also stages the FM partial

    hipLaunchKernelGGL(precompute_kernel, dim3(1151), dim3(64), 0, stream,
                       emb1, emb2, emb3, cont_w, cont_b, w1, b1);

    hipLaunchKernelGGL(phase1_kernel, dim3(2048), dim3(256), 0, stream,
                       x, emb0, lin0, emb1, lin1, emb2, lin2, emb3, lin3,
                       cont_w, cont_b, clin_w, clin_b, fin_bias, w1,
                       outp);

    hipLaunchKernelGGL(phase2_kernel, dim3(2048), dim3(256), 0, stream,
                       w2, b2, g1, beta1);

    hipLaunchKernelGGL(phase3_kernel, dim3(1024), dim3(256), 0, stream,
                       w_out, b_out, g2, beta2, outp);
}